// Round 15
// baseline (472.089 us; speedup 1.0000x reference)
//
#include <hip/hip_runtime.h>
#include <cstdint>

#define NN   100000
#define EE   1600000
#define EMBD 256
#define DD   128
#define BBB  4096
#define LLL  50
#define NCLS 10

#define NB   196                  /* coarse buckets of 512 dst nodes */
#define BSH  9
#define EPB  4096                 /* edges per cnt_k/bin_k block */

#define FIXS 1048576.0f           /* 2^20 fixed-point scale for spmm accum */
#define INVS (1.0f / 1048576.0f)

typedef __attribute__((ext_vector_type(8))) short bf16x8;
typedef __attribute__((ext_vector_type(4))) float f32x4;

__device__ __forceinline__ ushort f2bf(float f) {
  uint32_t u = __float_as_uint(f);
  u += 0x7fffu + ((u >> 16) & 1u);        // round-to-nearest-even
  return (ushort)(u >> 16);
}
__device__ __forceinline__ float bf2f(ushort h) {
  return __uint_as_float(((uint32_t)h) << 16);
}

// ---------------------------------------------------------------------------
// fp32 tiled GEMM (gather-GEMM): C[M,BN(grid.y)] = A@W (+bias)
//  grid.z splits K into chunks of kper; chunk z writes C + z*M*ldc.
//  bidxg!=null: gather-A mode: A(r,k) =
//      k<3200 ? Z[bidx[r*50 + k/64]*64 + k%64] : S[r*64 + k%64]
// ---------------------------------------------------------------------------
template<int BM, int BN, int BK, int TM, int TN>
__global__ __launch_bounds__(256)
void gemm_f32(const float* __restrict__ Av, int lda,
              const float* __restrict__ W, int ldw,
              const float* __restrict__ bias,
              float* __restrict__ Cv, int ldc,
              int M, int ktot, int kper,
              const int* __restrict__ bidxg,
              const float* __restrict__ Sg)
{
  constexpr int TX = BN / TN;
  constexpr int TY = BM / TM;
  static_assert(TX * TY == 256, "thread mapping");
  static_assert(TN % 4 == 0, "epilogue uses 4-wide vectors");
  constexpr int AQ = BK / 4;
  constexpr int ALOADS = (BM * AQ) / 256;
  static_assert((BM * AQ) % 256 == 0, "A-tile load mapping");
  constexpr int WQ4 = BN / 4;
  constexpr int WLOADS = (BK * WQ4) / 256;
  static_assert((BK * WQ4) % 256 == 0, "W-tile load mapping");

  __shared__ float As[BK][BM + 4];
  __shared__ float Ws[BK][BN];

  const int tid = threadIdx.x;
  const int tx = tid % TX, ty = tid / TX;
  const int bm0 = blockIdx.x * BM;
  const int bn0 = blockIdx.y * BN;
  const int z = blockIdx.z;
  const int koff = z * kper;
  int kc = ktot - koff; if (kc > kper) kc = kper;
  W += bn0 + (size_t)koff * ldw;
  Cv += (size_t)z * (size_t)M * ldc;
  const float* biasp = bias ? bias + bn0 : nullptr;

  float acc[TM][TN];
#pragma unroll
  for (int i = 0; i < TM; ++i)
#pragma unroll
    for (int j = 0; j < TN; ++j) acc[i][j] = 0.f;

  for (int kt = 0; kt < kc; kt += BK) {
#pragma unroll
    for (int p = 0; p < ALOADS; ++p) {
      int f = tid + p * 256;
      int row = f / AQ, q = f % AQ;
      int arow = bm0 + row;
      float4 av = make_float4(0.f, 0.f, 0.f, 0.f);
      if (arow < M) {
        if (bidxg) {
          int k = koff + kt + (q << 2);
          int l = k >> 6, jj = k & 63;
          const float* ap = (l < LLL)
              ? (Av + (size_t)bidxg[arow * LLL + l] * 64 + jj)
              : (Sg + (size_t)arow * 64 + jj);
          av = *(const float4*)ap;
        } else {
          av = *(const float4*)(Av + (long long)arow * lda + koff + kt + (q << 2));
        }
      }
      As[(q << 2) + 0][row] = av.x;
      As[(q << 2) + 1][row] = av.y;
      As[(q << 2) + 2][row] = av.z;
      As[(q << 2) + 3][row] = av.w;
    }
#pragma unroll
    for (int p = 0; p < WLOADS; ++p) {
      int f = tid + p * 256;
      int krow = f / WQ4, c4 = f % WQ4;
      *(float4*)&Ws[krow][c4 << 2] =
          *(const float4*)(W + (long long)(kt + krow) * ldw + (c4 << 2));
    }
    __syncthreads();
#pragma unroll
    for (int kk = 0; kk < BK; ++kk) {
      float a[TM], b[TN];
      if constexpr (TM % 4 == 0) {
#pragma unroll
        for (int i = 0; i < TM; i += 4)
          *(float4*)&a[i] = *(const float4*)&As[kk][ty * TM + i];
      } else {
#pragma unroll
        for (int i = 0; i < TM; ++i) a[i] = As[kk][ty * TM + i];
      }
#pragma unroll
      for (int j = 0; j < TN; j += 4)
        *(float4*)&b[j] = *(const float4*)&Ws[kk][tx * TN + j];
#pragma unroll
      for (int i = 0; i < TM; ++i)
#pragma unroll
        for (int j = 0; j < TN; ++j)
          acc[i][j] = fmaf(a[i], b[j], acc[i][j]);
    }
    __syncthreads();
  }

#pragma unroll
  for (int i = 0; i < TM; ++i) {
    int r = bm0 + ty * TM + i;
    if (r >= M) continue;
#pragma unroll
    for (int j4 = 0; j4 < TN; j4 += 4) {
      float4 v = make_float4(acc[i][j4], acc[i][j4 + 1],
                             acc[i][j4 + 2], acc[i][j4 + 3]);
      if (biasp != nullptr) {
        v.x += biasp[tx * TN + j4 + 0]; v.y += biasp[tx * TN + j4 + 1];
        v.z += biasp[tx * TN + j4 + 2]; v.w += biasp[tx * TN + j4 + 3];
      }
      *(float4*)(Cv + (long long)r * ldc + bn0 + tx * TN + j4) = v;
    }
  }
}

// ---------------------------------------------------------------------------
// MFMA QP GEMM v2: [Q|P] = A1[M,256] @ Wab[256,128] + bab, bf16x2-split,
// 3 products (hi*hi + hi*lo + lo*hi) -> ~1e-5 relative (fp32-class).
// BM=128/block; wave w owns rows [bm0+32w, +32) = 2 row-tiles -> 48 MFMAs
// per kt per wave. LDS A-planes padded [40] (80B stride, b128-aligned).
// C/D layout (m89-verified): col=lane&15, row=(lane>>4)*4+reg.
// ---------------------------------------------------------------------------
__global__ __launch_bounds__(256)
void gemm_qp_mfma(const float* __restrict__ A1,
                  const ushort* __restrict__ Wfh,
                  const ushort* __restrict__ Wfl,
                  const float* __restrict__ bab,
                  float* __restrict__ Qb, float* __restrict__ Pb, int M)
{
  __shared__ ushort LAh[128][40];
  __shared__ ushort LAl[128][40];
  const int tid = threadIdx.x;
  const int w = tid >> 6, l = tid & 63;
  const int bm0 = blockIdx.x * 128;
  const int srow = tid >> 1;                      // staging row (0..127)
  const int skh = (tid & 1) << 4;                 // staging k-half (0 or 16)
  const int fk = (l >> 4) << 3;                   // A-frag k offset

  f32x4 acc[2][8];
#pragma unroll
  for (int rt = 0; rt < 2; ++rt)
#pragma unroll
    for (int c = 0; c < 8; ++c) acc[rt][c] = (f32x4){0.f, 0.f, 0.f, 0.f};

  for (int kt8 = 0; kt8 < 8; ++kt8) {
    // ---- stage A tile [128][32] -> hi/lo bf16 planes (16 fp32/thread) ----
    {
      int grow = bm0 + srow;
      float x[16];
      if (grow < M) {
        const float* ap = A1 + (size_t)grow * 256 + (kt8 << 5) + skh;
        *(float4*)&x[0]  = *(const float4*)ap;
        *(float4*)&x[4]  = *(const float4*)(ap + 4);
        *(float4*)&x[8]  = *(const float4*)(ap + 8);
        *(float4*)&x[12] = *(const float4*)(ap + 12);
      } else {
#pragma unroll
        for (int j = 0; j < 16; ++j) x[j] = 0.f;
      }
      ushort h[16], lo[16];
#pragma unroll
      for (int j = 0; j < 16; ++j) {
        h[j] = f2bf(x[j]);
        lo[j] = f2bf(x[j] - bf2f(h[j]));
      }
      *(bf16x8*)&LAh[srow][skh]     = *(bf16x8*)&h[0];
      *(bf16x8*)&LAh[srow][skh + 8] = *(bf16x8*)&h[8];
      *(bf16x8*)&LAl[srow][skh]     = *(bf16x8*)&lo[0];
      *(bf16x8*)&LAl[srow][skh + 8] = *(bf16x8*)&lo[8];
    }
    __syncthreads();

    bf16x8 ah[2], al[2];
#pragma unroll
    for (int rt = 0; rt < 2; ++rt) {
      int frow = (w << 5) + (rt << 4) + (l & 15);
      ah[rt] = *(const bf16x8*)&LAh[frow][fk];
      al[rt] = *(const bf16x8*)&LAl[frow][fk];
    }
#pragma unroll
    for (int ct = 0; ct < 8; ++ct) {
      size_t off = ((size_t)((kt8 << 3) + ct) * 64 + l) << 3;
      bf16x8 bh = *(const bf16x8*)(Wfh + off);
      bf16x8 bl = *(const bf16x8*)(Wfl + off);
#pragma unroll
      for (int rt = 0; rt < 2; ++rt) {
        acc[rt][ct] = __builtin_amdgcn_mfma_f32_16x16x32_bf16(ah[rt], bh, acc[rt][ct], 0, 0, 0);
        acc[rt][ct] = __builtin_amdgcn_mfma_f32_16x16x32_bf16(ah[rt], bl, acc[rt][ct], 0, 0, 0);
        acc[rt][ct] = __builtin_amdgcn_mfma_f32_16x16x32_bf16(al[rt], bh, acc[rt][ct], 0, 0, 0);
      }
    }
    __syncthreads();
  }

  // ---- epilogue: split-store Q (cols 0-63) / P (cols 64-127) compact ----
#pragma unroll
  for (int rt = 0; rt < 2; ++rt) {
    const int r0 = bm0 + (w << 5) + (rt << 4) + ((l >> 4) << 2);
#pragma unroll
    for (int ct = 0; ct < 8; ++ct) {
      int gcol = (ct << 4) + (l & 15);
      float bia = bab[gcol];
      float* dst = (gcol < 64) ? (Qb + gcol) : (Pb + (gcol - 64));
#pragma unroll
      for (int r = 0; r < 4; ++r) {
        int grow = r0 + r;
        if (grow < M) dst[(size_t)grow * 64] = acc[rt][ct][r] + bia;
      }
    }
  }
}

// Pack Wab[256,128] into per-lane MFMA fragment order, bf16 hi/lo planes.
__global__ __launch_bounds__(256)
void wfrag_k(const float* __restrict__ Wab, ushort* __restrict__ Wfh,
             ushort* __restrict__ Wfl)
{
  int t = blockIdx.x * 256 + threadIdx.x;   // 4096 total
  if (t >= 4096) return;
  int f = t >> 6, l = t & 63;
  int kt = f >> 3, ct = f & 7;
  int row0 = (kt << 5) + ((l >> 4) << 3);
  int col = (ct << 4) + (l & 15);
  ushort h[8], lo[8];
#pragma unroll
  for (int j = 0; j < 8; ++j) {
    float x = Wab[(row0 + j) * 128 + col];
    h[j] = f2bf(x);
    lo[j] = f2bf(x - bf2f(h[j]));
  }
  size_t off = ((size_t)t) << 3;
  *(bf16x8*)(Wfh + off) = *(bf16x8*)h;
  *(bf16x8*)(Wfl + off) = *(bf16x8*)lo;
}

// ---------------------------------------------------------------------------
// Weight fusion stage 1: T1 = wgc1@wgc2, T2 = lin1@wgc2, ta = bgc1@wgc2,
// tb = lin1b@wgc2
// ---------------------------------------------------------------------------
__global__ __launch_bounds__(256)
void fuse1_k(const float* __restrict__ wgc1, const float* __restrict__ lin1,
             const float* __restrict__ bgc1, const float* __restrict__ lin1b,
             const float* __restrict__ wgc2,
             float* __restrict__ T1, float* __restrict__ T2,
             float* __restrict__ ta, float* __restrict__ tb)
{
  int t = blockIdx.x * 256 + threadIdx.x;
  const float* Arow; float* outp; int n;
  if (t < 32768)      { n = t & 127; Arow = wgc1 + (t >> 7) * 128; outp = T1 + t; }
  else if (t < 65536) { int u = t - 32768; n = u & 127; Arow = lin1 + (u >> 7) * 128; outp = T2 + u; }
  else if (t < 65664) { n = t - 65536; Arow = bgc1;  outp = ta + n; }
  else if (t < 65792) { n = t - 65664; Arow = lin1b; outp = tb + n; }
  else return;
  float s = 0.f;
  for (int k = 0; k < 128; ++k) s = fmaf(Arow[k], wgc2[k * 128 + n], s);
  *outp = s;
}

// ---------------------------------------------------------------------------
// Weight fusion stage 2
// ---------------------------------------------------------------------------
__global__ __launch_bounds__(256)
void fuse2_k(const float* __restrict__ T1, const float* __restrict__ T2,
             const float* __restrict__ ta, const float* __restrict__ tb,
             const float* __restrict__ bgc2, const float* __restrict__ w2,
             float* __restrict__ Wab, float* __restrict__ bab,
             float* __restrict__ bcv)
{
  int t = blockIdx.x * 256 + threadIdx.x;
  const float* Arow; float* outp; int j;
  if (t < 32768) {
    int c = t & 127; j = c & 63;
    Arow = (c < 64 ? T1 : T2) + (t >> 7) * 128;
    outp = Wab + t;
  } else if (t < 32896) {
    int c = t - 32768; j = c & 63; Arow = (c < 64) ? ta : tb; outp = bab + c;
  } else if (t < 32960) {
    j = t - 32896; Arow = bgc2; outp = bcv + j;
  } else return;
  float s = 0.f;
  for (int k = 0; k < 128; ++k) s = fmaf(Arow[k], w2[k * 64 + j], s);
  *outp = s;
}

// ---------------------------------------------------------------------------
// CSR build v3: coarse count -> 1-block scan -> bin -> per-bucket sort.
// ---------------------------------------------------------------------------
__global__ __launch_bounds__(256)
void cnt_k(const int* __restrict__ edst, int* __restrict__ gbkt)
{
  __shared__ int l[NB];
  const int tid = threadIdx.x;
  for (int i = tid; i < NB; i += 256) l[i] = 0;
  __syncthreads();
  const int e0 = blockIdx.x * EPB;
  const int e1 = min(EE, e0 + EPB);
#pragma unroll
  for (int u = 0; u < 16; ++u) {
    int e = e0 + u * 256 + tid;
    if (e < e1) atomicAdd(&l[edst[e] >> BSH], 1);
  }
  __syncthreads();
  for (int i = tid; i < NB; i += 256)
    if (l[i]) atomicAdd(&gbkt[i], l[i]);
}

__global__ __launch_bounds__(256)
void scanB_k(const int* __restrict__ gbkt, int* __restrict__ bbase,
             int* __restrict__ gcur, int* __restrict__ rp)
{
  __shared__ int s[256];
  int t = threadIdx.x;
  int v = (t < NB) ? gbkt[t] : 0;
  s[t] = v;
  __syncthreads();
  for (int off = 1; off < 256; off <<= 1) {
    int u = (t >= off) ? s[t - off] : 0;
    __syncthreads();
    s[t] += u;
    __syncthreads();
  }
  if (t < NB) {
    int ex = s[t] - v;
    bbase[t] = ex;
    gcur[t] = ex;
  }
  if (t == 0) { bbase[NB] = EE; rp[NN] = EE; }
}

__global__ __launch_bounds__(256)
void bin_k(const int* __restrict__ edst, const int* __restrict__ esrc,
           const float* __restrict__ ew, int* __restrict__ gcur,
           int4* __restrict__ ebd)
{
  __shared__ int lcnt[NB];
  __shared__ int lbase[NB];
  const int tid = threadIdx.x;
  const int e0 = blockIdx.x * EPB;
  const int e1 = min(EE, e0 + EPB);
  for (int i = tid; i < NB; i += 256) lcnt[i] = 0;
  __syncthreads();
  int dv[16], sv[16], wv[16];
#pragma unroll
  for (int u = 0; u < 16; ++u) {
    int e = e0 + u * 256 + tid;
    if (e < e1) {
      dv[u] = edst[e];
      sv[u] = esrc[e];
      wv[u] = __float_as_int(ew[e]);
      atomicAdd(&lcnt[dv[u] >> BSH], 1);
    } else dv[u] = -1;
  }
  __syncthreads();
  for (int i = tid; i < NB; i += 256) {
    lbase[i] = atomicAdd(&gcur[i], lcnt[i]);
    lcnt[i] = 0;
  }
  __syncthreads();
#pragma unroll
  for (int u = 0; u < 16; ++u) {
    if (dv[u] >= 0) {
      int c = dv[u] >> BSH;
      int k = atomicAdd(&lcnt[c], 1);
      int4 p; p.x = dv[u]; p.y = sv[u]; p.z = wv[u]; p.w = 0;
      ebd[lbase[c] + k] = p;
    }
  }
}

__global__ __launch_bounds__(256)
void sort_k(const int4* __restrict__ ebd, const int* __restrict__ bbase,
            int* __restrict__ rp, int2* __restrict__ sw)
{
  __shared__ int hist[512];
  __shared__ int excl[512];
  __shared__ int s2[256];
  __shared__ int lcur[512];
  const int c = blockIdx.x;
  const int n0 = c << BSH;
  const int n1 = min(NN, n0 + 512);
  const int nn = n1 - n0;
  const int tid = threadIdx.x;
  for (int i = tid; i < 512; i += 256) { hist[i] = 0; lcur[i] = 0; }
  __syncthreads();
  const int b0 = bbase[c];
  const int b1 = bbase[c + 1];
  for (int i = b0 + tid; i < b1; i += 256)
    atomicAdd(&hist[ebd[i].x - n0], 1);
  __syncthreads();
  int a0 = hist[2 * tid], a1 = hist[2 * tid + 1];
  s2[tid] = a0 + a1;
  __syncthreads();
  for (int off = 1; off < 256; off <<= 1) {
    int u = (tid >= off) ? s2[tid - off] : 0;
    __syncthreads();
    s2[tid] += u;
    __syncthreads();
  }
  int pe = tid ? s2[tid - 1] : 0;
  excl[2 * tid] = pe;
  excl[2 * tid + 1] = pe + a0;
  if (2 * tid < nn)     rp[n0 + 2 * tid]     = b0 + pe;
  if (2 * tid + 1 < nn) rp[n0 + 2 * tid + 1] = b0 + pe + a0;
  __syncthreads();
  for (int i = b0 + tid; i < b1; i += 256) {
    int4 p = ebd[i];
    int li = p.x - n0;
    int k = atomicAdd(&lcur[li], 1);
    int2 q; q.x = p.y; q.y = p.z;
    sw[b0 + excl[li] + k] = q;
  }
}

// ---------------------------------------------------------------------------
// CSR spmm on compact 64-wide f32 rows: one wave per dst node, lane owns one
// column. 16-deep load batching for MLP. Int fixed-point accumulate ->
// bit-deterministic.
//  MODE 1: out = acc*INVS + bias[lane]
//  MODE 2: out = n[d]*P[d,lane] + (1-n[d])*acc*INVS + bias[lane]
// ---------------------------------------------------------------------------
template<int MODE>
__global__ __launch_bounds__(256)
void spmm64(const int* __restrict__ rp, const int2* __restrict__ sw,
            const float* __restrict__ Gf, float* __restrict__ xout,
            const float* __restrict__ bias, const float* __restrict__ npar,
            const float* __restrict__ Pb)
{
  int widx = blockIdx.x * 4 + (threadIdx.x >> 6);
  if (widx >= NN) return;
  int lane = threadIdx.x & 63;
  int e0 = rp[widx], e1 = rp[widx + 1];
  int acc = 0;
  int j = e0;
  for (; j + 16 <= e1; j += 16) {
    int2 q[16];
#pragma unroll
    for (int u = 0; u < 16; ++u) q[u] = sw[j + u];
    float gv[16];
#pragma unroll
    for (int u = 0; u < 16; ++u)
      gv[u] = Gf[(size_t)q[u].x * 64 + lane];
#pragma unroll
    for (int u = 0; u < 16; ++u)
      acc += __float2int_rn(gv[u] * __int_as_float(q[u].y) * FIXS);
  }
  for (; j + 8 <= e1; j += 8) {
    float gv[8], wv[8];
#pragma unroll
    for (int u = 0; u < 8; ++u) {
      int2 q = sw[j + u];
      wv[u] = __int_as_float(q.y);
      gv[u] = Gf[(size_t)q.x * 64 + lane];
    }
#pragma unroll
    for (int u = 0; u < 8; ++u)
      acc += __float2int_rn(gv[u] * wv[u] * FIXS);
  }
  for (; j < e1; ++j) {
    int2 q = sw[j];
    acc += __float2int_rn(Gf[(size_t)q.x * 64 + lane] *
                          __int_as_float(q.y) * FIXS);
  }
  float v = (float)acc * INVS;
  if (MODE == 1) {
    xout[(size_t)widx * 64 + lane] = v + bias[lane];
  } else {
    float nv = npar[widx];
    float p = Pb[(size_t)widx * 64 + lane];
    xout[(size_t)widx * 64 + lane] = nv * p + (1.f - nv) * v + bias[lane];
  }
}

// ---------------------------------------------------------------------------
// S[b,:] = sum_l Z[bidx[b,l],:] - 49*b2
// ---------------------------------------------------------------------------
__global__ __launch_bounds__(256)
void sumS_k(const float* __restrict__ Z, const int* __restrict__ bidx,
            const float* __restrict__ b2, float* __restrict__ S)
{
  int wv = threadIdx.x >> 6;
  int lane = threadIdx.x & 63;
  int b = blockIdx.x * 4 + wv;
  if (b >= BBB) return;
  const int* bi = bidx + (size_t)b * LLL;
  float s = 0.f;
  for (int l = 0; l < LLL; ++l)
    s += Z[(size_t)bi[l] * 64 + lane];
  S[(size_t)b * 64 + lane] = s - 49.f * b2[lane];
}

// ---------------------------------------------------------------------------
// sel = sum_{z=0..7} P8[z] + l1b  (fixed order -> deterministic)
// ---------------------------------------------------------------------------
__global__ __launch_bounds__(256)
void reduce8_k(const float* __restrict__ P8, const float* __restrict__ l1b,
               float* __restrict__ sel)
{
  int t = blockIdx.x * 256 + threadIdx.x;
  if (t >= BBB * 32) return;
  int r = t >> 5, c4 = t & 31;
  size_t off = (size_t)r * 128 + (c4 << 2);
  const size_t zs = (size_t)BBB * 128;
  float4 o = *(const float4*)(P8 + off);
#pragma unroll
  for (int z = 1; z < 8; ++z) {
    float4 s = *(const float4*)(P8 + z * zs + off);
    o.x += s.x; o.y += s.y; o.z += s.z; o.w += s.w;
  }
  float4 b = *(const float4*)(l1b + (c4 << 2));
  o.x += b.x; o.y += b.y; o.z += b.z; o.w += b.w;
  *(float4*)(sel + off) = o;
}

// ---------------------------------------------------------------------------
// Classifier + argmax (first-max tie-break, matches jnp.argmax).
// ---------------------------------------------------------------------------
__global__ __launch_bounds__(256)
void cls_k(const float* __restrict__ sel, const float* __restrict__ Wc,
           const float* __restrict__ bc, float* __restrict__ outIdx)
{
  int wv = threadIdx.x >> 6;
  int lane = threadIdx.x & 63;
  int b = blockIdx.x * 4 + wv;
  if (b >= BBB) return;
  float logit = -1e30f;
  if (lane < NCLS) {
    float s = bc[lane];
    const float* sr = sel + (size_t)b * DD;
    for (int d = 0; d < DD; ++d) s = fmaf(sr[d], Wc[d * NCLS + lane], s);
    logit = s;
  }
  float best = -1e30f; int bi = 0;
  for (int c = 0; c < NCLS; ++c) {
    float v = __shfl(logit, c, 64);
    if (v > best) { best = v; bi = c; }
  }
  if (lane == 0) outIdx[b] = (float)bi;
}

// ---------------------------------------------------------------------------
extern "C" void kernel_launch(void* const* d_in, const int* in_sizes, int n_in,
                              void* d_out, int out_size, void* d_ws, size_t ws_size,
                              hipStream_t stream)
{
  const float* A1    = (const float*)d_in[0];
  const int*   esrc  = (const int*)d_in[1];
  const int*   edst  = (const int*)d_in[2];
  const float* ew    = (const float*)d_in[3];
  const int*   bidx  = (const int*)d_in[4];   // [B,1,L] == [B*L]
  const float* wgc1  = (const float*)d_in[5];
  const float* bgc1  = (const float*)d_in[6];
  const float* wgc2  = (const float*)d_in[7];
  const float* bgc2  = (const float*)d_in[8];
  const float* npar  = (const float*)d_in[9];
  const float* lin1  = (const float*)d_in[10];
  const float* lin1b = (const float*)d_in[11];
  const float* w2    = (const float*)d_in[12];
  const float* b2    = (const float*)d_in[13];
  const float* l1w   = (const float*)d_in[14];
  const float* l1b   = (const float*)d_in[15];
  const float* clsw  = (const float*)d_in[16];
  const float* clsb  = (const float*)d_in[17];

  float* out = (float*)d_out;
  float* sel = out + BBB;

  // workspace layout (peak ~92.0 MB; proven floor from round 1 is 104.67 MB)
  uint8_t* ws   = (uint8_t*)d_ws;
  int4*    ebd  = (int4*) (ws);                 // 25.6 MB (CSR build)
  float*   Qb   = (float*)(ws);                 // 25.6 MB (after sort_k)
  float*   Z    = (float*)(ws);                 // 25.6 MB (after spmm1)
  float*   Pb   = (float*)(ws + 25600000);      // 25.6 MB
  float*   G    = (float*)(ws + 51200000);      // 25.6 MB
  float*   P8   = (float*)(ws + 51200000);      // 16.8 MB (after spmm2)
  int2*    sw   = (int2*) (ws + 76800000);      // 12.8 MB packed (src,w)
  int*     rp   = (int*)  (ws + 89600000);      //  0.4 MB (N+1)
  int*     gbkt = (int*)  (ws + 90000016);      //  784 B
  int*     gcur = (int*)  (ws + 90001040);      //  784 B
  int*     bbase= (int*)  (ws + 90002064);      //  788 B
  float*   S    = (float*)(ws + 90400528);      //  1.0 MB [B,64]
  float*   T1   = (float*)(ws + 91449104);      // 128 KB
  float*   T2   = (float*)(ws + 91580176);      // 128 KB
  float*   Wab  = (float*)(ws + 91711248);      // 128 KB [256,128]
  float*   ta   = (float*)(ws + 91842320);      // 512 B
  float*   tb   = (float*)(ws + 91842832);      // 512 B
  float*   bab  = (float*)(ws + 91843344);      // 512 B [128]
  float*   bcv  = (float*)(ws + 91843856);      // 256 B [64]
  ushort*  Wfh  = (ushort*)(ws + 91844112);     //  64 KB W frag hi
  ushort*  Wfl  = (ushort*)(ws + 91909648);     //  64 KB W frag lo

  dim3 blk(256);
  const int gEB = (EE + EPB - 1) / EPB;         // 391

  // ---- weight fusion + MFMA fragment pack ----
  hipLaunchKernelGGL(fuse1_k, dim3(257), blk, 0, stream,
      wgc1, lin1, bgc1, lin1b, wgc2, T1, T2, ta, tb);
  hipLaunchKernelGGL(fuse2_k, dim3(129), blk, 0, stream,
      T1, T2, ta, tb, bgc2, w2, Wab, bab, bcv);
  hipLaunchKernelGGL(wfrag_k, dim3(16), blk, 0, stream, Wab, Wfh, Wfl);

  // ---- CSR build (coarse count -> scan -> bin -> per-bucket sort) ----
  hipMemsetAsync(gbkt, 0, NB * 4, stream);
  hipLaunchKernelGGL(cnt_k, dim3(gEB), blk, 0, stream, edst, gbkt);
  hipLaunchKernelGGL(scanB_k, dim3(1), blk, 0, stream, gbkt, bbase, gcur, rp);
  hipLaunchKernelGGL(bin_k, dim3(gEB), blk, 0, stream, edst, esrc, ew, gcur, ebd);
  hipLaunchKernelGGL(sort_k, dim3(NB), blk, 0, stream, ebd, bbase, rp, sw);

  // ---- Q|P = A1 @ Wab + bab via bf16x2-split MFMA (compact [N,64] each) ----
  hipLaunchKernelGGL(gemm_qp_mfma, dim3((NN + 127) / 128), blk, 0, stream,
      A1, Wfh, Wfl, bab, Qb, Pb, NN);

  // ---- G = n*P + (1-n)*spmm(Q) + bc ----
  hipLaunchKernelGGL((spmm64<2>), dim3(NN / 4), blk, 0, stream,
      rp, sw, Qb, G, bcv, npar, Pb);

  // ---- Z = spmm(G) + b2  [N,64] (overwrites Qbuf) ----
  hipLaunchKernelGGL((spmm64<1>), dim3(NN / 4), blk, 0, stream,
      rp, sw, G, Z, b2, (const float*)nullptr, (const float*)nullptr);

  // ---- S[b] = sum_l Z[bidx[b,l]] - 49*b2 ----
  hipLaunchKernelGGL(sumS_k, dim3(BBB / 4), blk, 0, stream, Z, bidx, b2, S);

  // ---- P8[z] = [gather(Z)|S] @ l1w (K-chunk z)  grid (64,2,8) ----
  hipLaunchKernelGGL((gemm_f32<64,64,32,4,4>), dim3(BBB / 64, 2, 8), blk, 0, stream,
      Z, 64, l1w, DD, (const float*)nullptr, P8, DD,
      BBB, (LLL + 1) * 64, 13 * 32, bidx, S);

  // ---- sel = sum_z P8[z] + l1b ----
  hipLaunchKernelGGL(reduce8_k, dim3(BBB * 32 / 256), blk, 0, stream, P8, l1b, sel);

  // ---- argmax(sel @ classifier + bias) -> out[0:B] ----
  hipLaunchKernelGGL(cls_k, dim3(BBB / 4), blk, 0, stream, sel, clsw, clsb, out);
}

// Round 16
// 369.841 us; speedup vs baseline: 1.2765x; 1.2765x over previous
//
#include <hip/hip_runtime.h>
#include <cstdint>

#define NN   100000
#define EE   1600000
#define EMBD 256
#define DD   128
#define BBB  4096
#define LLL  50
#define NCLS 10

#define NB   196                  /* coarse buckets of 512 dst nodes */
#define BSH  9
#define EPB  4096                 /* edges per cnt_k/bin_k block */

#define FIXS 1048576.0f           /* 2^20 fixed-point scale for spmm accum */
#define INVS (1.0f / 1048576.0f)

typedef __attribute__((ext_vector_type(8))) short bf16x8;
typedef __attribute__((ext_vector_type(4))) float f32x4;

__device__ __forceinline__ ushort f2bf(float f) {
  uint32_t u = __float_as_uint(f);
  u += 0x7fffu + ((u >> 16) & 1u);        // round-to-nearest-even
  return (ushort)(u >> 16);
}
__device__ __forceinline__ float bf2f(ushort h) {
  return __uint_as_float(((uint32_t)h) << 16);
}

// ---------------------------------------------------------------------------
// fp32 tiled GEMM (gather-GEMM): C[M,BN(grid.y)] = A@W (+bias)
//  grid.z splits K into chunks of kper; chunk z writes C + z*M*ldc.
//  bidxg!=null: gather-A mode: A(r,k) =
//      k<3200 ? Z[bidx[r*50 + k/64]*64 + k%64] : S[r*64 + k%64]
// ---------------------------------------------------------------------------
template<int BM, int BN, int BK, int TM, int TN>
__global__ __launch_bounds__(256)
void gemm_f32(const float* __restrict__ Av, int lda,
              const float* __restrict__ W, int ldw,
              const float* __restrict__ bias,
              float* __restrict__ Cv, int ldc,
              int M, int ktot, int kper,
              const int* __restrict__ bidxg,
              const float* __restrict__ Sg)
{
  constexpr int TX = BN / TN;
  constexpr int TY = BM / TM;
  static_assert(TX * TY == 256, "thread mapping");
  static_assert(TN % 4 == 0, "epilogue uses 4-wide vectors");
  constexpr int AQ = BK / 4;
  constexpr int ALOADS = (BM * AQ) / 256;
  static_assert((BM * AQ) % 256 == 0, "A-tile load mapping");
  constexpr int WQ4 = BN / 4;
  constexpr int WLOADS = (BK * WQ4) / 256;
  static_assert((BK * WQ4) % 256 == 0, "W-tile load mapping");

  __shared__ float As[BK][BM + 4];
  __shared__ float Ws[BK][BN];

  const int tid = threadIdx.x;
  const int tx = tid % TX, ty = tid / TX;
  const int bm0 = blockIdx.x * BM;
  const int bn0 = blockIdx.y * BN;
  const int z = blockIdx.z;
  const int koff = z * kper;
  int kc = ktot - koff; if (kc > kper) kc = kper;
  W += bn0 + (size_t)koff * ldw;
  Cv += (size_t)z * (size_t)M * ldc;
  const float* biasp = bias ? bias + bn0 : nullptr;

  float acc[TM][TN];
#pragma unroll
  for (int i = 0; i < TM; ++i)
#pragma unroll
    for (int j = 0; j < TN; ++j) acc[i][j] = 0.f;

  for (int kt = 0; kt < kc; kt += BK) {
#pragma unroll
    for (int p = 0; p < ALOADS; ++p) {
      int f = tid + p * 256;
      int row = f / AQ, q = f % AQ;
      int arow = bm0 + row;
      float4 av = make_float4(0.f, 0.f, 0.f, 0.f);
      if (arow < M) {
        if (bidxg) {
          int k = koff + kt + (q << 2);
          int l = k >> 6, jj = k & 63;
          const float* ap = (l < LLL)
              ? (Av + (size_t)bidxg[arow * LLL + l] * 64 + jj)
              : (Sg + (size_t)arow * 64 + jj);
          av = *(const float4*)ap;
        } else {
          av = *(const float4*)(Av + (long long)arow * lda + koff + kt + (q << 2));
        }
      }
      As[(q << 2) + 0][row] = av.x;
      As[(q << 2) + 1][row] = av.y;
      As[(q << 2) + 2][row] = av.z;
      As[(q << 2) + 3][row] = av.w;
    }
#pragma unroll
    for (int p = 0; p < WLOADS; ++p) {
      int f = tid + p * 256;
      int krow = f / WQ4, c4 = f % WQ4;
      *(float4*)&Ws[krow][c4 << 2] =
          *(const float4*)(W + (long long)(kt + krow) * ldw + (c4 << 2));
    }
    __syncthreads();
#pragma unroll
    for (int kk = 0; kk < BK; ++kk) {
      float a[TM], b[TN];
      if constexpr (TM % 4 == 0) {
#pragma unroll
        for (int i = 0; i < TM; i += 4)
          *(float4*)&a[i] = *(const float4*)&As[kk][ty * TM + i];
      } else {
#pragma unroll
        for (int i = 0; i < TM; ++i) a[i] = As[kk][ty * TM + i];
      }
#pragma unroll
      for (int j = 0; j < TN; j += 4)
        *(float4*)&b[j] = *(const float4*)&Ws[kk][tx * TN + j];
#pragma unroll
      for (int i = 0; i < TM; ++i)
#pragma unroll
        for (int j = 0; j < TN; ++j)
          acc[i][j] = fmaf(a[i], b[j], acc[i][j]);
    }
    __syncthreads();
  }

#pragma unroll
  for (int i = 0; i < TM; ++i) {
    int r = bm0 + ty * TM + i;
    if (r >= M) continue;
#pragma unroll
    for (int j4 = 0; j4 < TN; j4 += 4) {
      float4 v = make_float4(acc[i][j4], acc[i][j4 + 1],
                             acc[i][j4 + 2], acc[i][j4 + 3]);
      if (biasp != nullptr) {
        v.x += biasp[tx * TN + j4 + 0]; v.y += biasp[tx * TN + j4 + 1];
        v.z += biasp[tx * TN + j4 + 2]; v.w += biasp[tx * TN + j4 + 3];
      }
      *(float4*)(Cv + (long long)r * ldc + bn0 + tx * TN + j4) = v;
    }
  }
}

// ---------------------------------------------------------------------------
// MFMA QP GEMM v2: [Q|P] = A1[M,256] @ Wab[256,128] + bab, bf16x2-split,
// 3 products (hi*hi + hi*lo + lo*hi) -> ~1e-5 relative (fp32-class).
// BM=128/block; wave w owns rows [bm0+32w, +32) = 2 row-tiles -> 48 MFMAs
// per kt per wave. LDS A-planes padded [40] (80B stride, b128-aligned).
// C/D layout (m89-verified): col=lane&15, row=(lane>>4)*4+reg.
// ---------------------------------------------------------------------------
__global__ __launch_bounds__(256)
void gemm_qp_mfma(const float* __restrict__ A1,
                  const ushort* __restrict__ Wfh,
                  const ushort* __restrict__ Wfl,
                  const float* __restrict__ bab,
                  float* __restrict__ Qb, float* __restrict__ Pb, int M)
{
  __shared__ ushort LAh[128][40];
  __shared__ ushort LAl[128][40];
  const int tid = threadIdx.x;
  const int w = tid >> 6, l = tid & 63;
  const int bm0 = blockIdx.x * 128;
  const int srow = tid >> 1;                      // staging row (0..127)
  const int skh = (tid & 1) << 4;                 // staging k-half (0 or 16)
  const int fk = (l >> 4) << 3;                   // A-frag k offset

  f32x4 acc[2][8];
#pragma unroll
  for (int rt = 0; rt < 2; ++rt)
#pragma unroll
    for (int c = 0; c < 8; ++c) acc[rt][c] = (f32x4){0.f, 0.f, 0.f, 0.f};

  for (int kt8 = 0; kt8 < 8; ++kt8) {
    // ---- stage A tile [128][32] -> hi/lo bf16 planes (16 fp32/thread) ----
    {
      int grow = bm0 + srow;
      float x[16];
      if (grow < M) {
        const float* ap = A1 + (size_t)grow * 256 + (kt8 << 5) + skh;
        *(float4*)&x[0]  = *(const float4*)ap;
        *(float4*)&x[4]  = *(const float4*)(ap + 4);
        *(float4*)&x[8]  = *(const float4*)(ap + 8);
        *(float4*)&x[12] = *(const float4*)(ap + 12);
      } else {
#pragma unroll
        for (int j = 0; j < 16; ++j) x[j] = 0.f;
      }
      ushort h[16], lo[16];
#pragma unroll
      for (int j = 0; j < 16; ++j) {
        h[j] = f2bf(x[j]);
        lo[j] = f2bf(x[j] - bf2f(h[j]));
      }
      *(bf16x8*)&LAh[srow][skh]     = *(bf16x8*)&h[0];
      *(bf16x8*)&LAh[srow][skh + 8] = *(bf16x8*)&h[8];
      *(bf16x8*)&LAl[srow][skh]     = *(bf16x8*)&lo[0];
      *(bf16x8*)&LAl[srow][skh + 8] = *(bf16x8*)&lo[8];
    }
    __syncthreads();

    bf16x8 ah[2], al[2];
#pragma unroll
    for (int rt = 0; rt < 2; ++rt) {
      int frow = (w << 5) + (rt << 4) + (l & 15);
      ah[rt] = *(const bf16x8*)&LAh[frow][fk];
      al[rt] = *(const bf16x8*)&LAl[frow][fk];
    }
#pragma unroll
    for (int ct = 0; ct < 8; ++ct) {
      size_t off = ((size_t)((kt8 << 3) + ct) * 64 + l) << 3;
      bf16x8 bh = *(const bf16x8*)(Wfh + off);
      bf16x8 bl = *(const bf16x8*)(Wfl + off);
#pragma unroll
      for (int rt = 0; rt < 2; ++rt) {
        acc[rt][ct] = __builtin_amdgcn_mfma_f32_16x16x32_bf16(ah[rt], bh, acc[rt][ct], 0, 0, 0);
        acc[rt][ct] = __builtin_amdgcn_mfma_f32_16x16x32_bf16(ah[rt], bl, acc[rt][ct], 0, 0, 0);
        acc[rt][ct] = __builtin_amdgcn_mfma_f32_16x16x32_bf16(al[rt], bh, acc[rt][ct], 0, 0, 0);
      }
    }
    __syncthreads();
  }

  // ---- epilogue: split-store Q (cols 0-63) / P (cols 64-127) compact ----
#pragma unroll
  for (int rt = 0; rt < 2; ++rt) {
    const int r0 = bm0 + (w << 5) + (rt << 4) + ((l >> 4) << 2);
#pragma unroll
    for (int ct = 0; ct < 8; ++ct) {
      int gcol = (ct << 4) + (l & 15);
      float bia = bab[gcol];
      float* dst = (gcol < 64) ? (Qb + gcol) : (Pb + (gcol - 64));
#pragma unroll
      for (int r = 0; r < 4; ++r) {
        int grow = r0 + r;
        if (grow < M) dst[(size_t)grow * 64] = acc[rt][ct][r] + bia;
      }
    }
  }
}

// Pack Wab[256,128] into per-lane MFMA fragment order, bf16 hi/lo planes.
__global__ __launch_bounds__(256)
void wfrag_k(const float* __restrict__ Wab, ushort* __restrict__ Wfh,
             ushort* __restrict__ Wfl)
{
  int t = blockIdx.x * 256 + threadIdx.x;   // 4096 total
  if (t >= 4096) return;
  int f = t >> 6, l = t & 63;
  int kt = f >> 3, ct = f & 7;
  int row0 = (kt << 5) + ((l >> 4) << 3);
  int col = (ct << 4) + (l & 15);
  ushort h[8], lo[8];
#pragma unroll
  for (int j = 0; j < 8; ++j) {
    float x = Wab[(row0 + j) * 128 + col];
    h[j] = f2bf(x);
    lo[j] = f2bf(x - bf2f(h[j]));
  }
  size_t off = ((size_t)t) << 3;
  *(bf16x8*)(Wfh + off) = *(bf16x8*)h;
  *(bf16x8*)(Wfl + off) = *(bf16x8*)lo;
}

// ---------------------------------------------------------------------------
// Weight fusion stage 1: T1 = wgc1@wgc2, T2 = lin1@wgc2, ta = bgc1@wgc2,
// tb = lin1b@wgc2
// ---------------------------------------------------------------------------
__global__ __launch_bounds__(256)
void fuse1_k(const float* __restrict__ wgc1, const float* __restrict__ lin1,
             const float* __restrict__ bgc1, const float* __restrict__ lin1b,
             const float* __restrict__ wgc2,
             float* __restrict__ T1, float* __restrict__ T2,
             float* __restrict__ ta, float* __restrict__ tb)
{
  int t = blockIdx.x * 256 + threadIdx.x;
  const float* Arow; float* outp; int n;
  if (t < 32768)      { n = t & 127; Arow = wgc1 + (t >> 7) * 128; outp = T1 + t; }
  else if (t < 65536) { int u = t - 32768; n = u & 127; Arow = lin1 + (u >> 7) * 128; outp = T2 + u; }
  else if (t < 65664) { n = t - 65536; Arow = bgc1;  outp = ta + n; }
  else if (t < 65792) { n = t - 65664; Arow = lin1b; outp = tb + n; }
  else return;
  float s = 0.f;
  for (int k = 0; k < 128; ++k) s = fmaf(Arow[k], wgc2[k * 128 + n], s);
  *outp = s;
}

// ---------------------------------------------------------------------------
// Weight fusion stage 2
// ---------------------------------------------------------------------------
__global__ __launch_bounds__(256)
void fuse2_k(const float* __restrict__ T1, const float* __restrict__ T2,
             const float* __restrict__ ta, const float* __restrict__ tb,
             const float* __restrict__ bgc2, const float* __restrict__ w2,
             float* __restrict__ Wab, float* __restrict__ bab,
             float* __restrict__ bcv)
{
  int t = blockIdx.x * 256 + threadIdx.x;
  const float* Arow; float* outp; int j;
  if (t < 32768) {
    int c = t & 127; j = c & 63;
    Arow = (c < 64 ? T1 : T2) + (t >> 7) * 128;
    outp = Wab + t;
  } else if (t < 32896) {
    int c = t - 32768; j = c & 63; Arow = (c < 64) ? ta : tb; outp = bab + c;
  } else if (t < 32960) {
    j = t - 32896; Arow = bgc2; outp = bcv + j;
  } else return;
  float s = 0.f;
  for (int k = 0; k < 128; ++k) s = fmaf(Arow[k], w2[k * 64 + j], s);
  *outp = s;
}

// ---------------------------------------------------------------------------
// CSR build v3: coarse count -> 1-block scan -> bin -> per-bucket sort.
// ---------------------------------------------------------------------------
__global__ __launch_bounds__(256)
void cnt_k(const int* __restrict__ edst, int* __restrict__ gbkt)
{
  __shared__ int l[NB];
  const int tid = threadIdx.x;
  for (int i = tid; i < NB; i += 256) l[i] = 0;
  __syncthreads();
  const int e0 = blockIdx.x * EPB;
  const int e1 = min(EE, e0 + EPB);
#pragma unroll
  for (int u = 0; u < 16; ++u) {
    int e = e0 + u * 256 + tid;
    if (e < e1) atomicAdd(&l[edst[e] >> BSH], 1);
  }
  __syncthreads();
  for (int i = tid; i < NB; i += 256)
    if (l[i]) atomicAdd(&gbkt[i], l[i]);
}

__global__ __launch_bounds__(256)
void scanB_k(const int* __restrict__ gbkt, int* __restrict__ bbase,
             int* __restrict__ gcur, int* __restrict__ rp)
{
  __shared__ int s[256];
  int t = threadIdx.x;
  int v = (t < NB) ? gbkt[t] : 0;
  s[t] = v;
  __syncthreads();
  for (int off = 1; off < 256; off <<= 1) {
    int u = (t >= off) ? s[t - off] : 0;
    __syncthreads();
    s[t] += u;
    __syncthreads();
  }
  if (t < NB) {
    int ex = s[t] - v;
    bbase[t] = ex;
    gcur[t] = ex;
  }
  if (t == 0) { bbase[NB] = EE; rp[NN] = EE; }
}

__global__ __launch_bounds__(256)
void bin_k(const int* __restrict__ edst, const int* __restrict__ esrc,
           const float* __restrict__ ew, int* __restrict__ gcur,
           int4* __restrict__ ebd)
{
  __shared__ int lcnt[NB];
  __shared__ int lbase[NB];
  const int tid = threadIdx.x;
  const int e0 = blockIdx.x * EPB;
  const int e1 = min(EE, e0 + EPB);
  for (int i = tid; i < NB; i += 256) lcnt[i] = 0;
  __syncthreads();
  int dv[16], sv[16], wv[16];
#pragma unroll
  for (int u = 0; u < 16; ++u) {
    int e = e0 + u * 256 + tid;
    if (e < e1) {
      dv[u] = edst[e];
      sv[u] = esrc[e];
      wv[u] = __float_as_int(ew[e]);
      atomicAdd(&lcnt[dv[u] >> BSH], 1);
    } else dv[u] = -1;
  }
  __syncthreads();
  for (int i = tid; i < NB; i += 256) {
    lbase[i] = atomicAdd(&gcur[i], lcnt[i]);
    lcnt[i] = 0;
  }
  __syncthreads();
#pragma unroll
  for (int u = 0; u < 16; ++u) {
    if (dv[u] >= 0) {
      int c = dv[u] >> BSH;
      int k = atomicAdd(&lcnt[c], 1);
      int4 p; p.x = dv[u]; p.y = sv[u]; p.z = wv[u]; p.w = 0;
      ebd[lbase[c] + k] = p;
    }
  }
}

__global__ __launch_bounds__(256)
void sort_k(const int4* __restrict__ ebd, const int* __restrict__ bbase,
            int* __restrict__ rp, int2* __restrict__ sw)
{
  __shared__ int hist[512];
  __shared__ int excl[512];
  __shared__ int s2[256];
  __shared__ int lcur[512];
  const int c = blockIdx.x;
  const int n0 = c << BSH;
  const int n1 = min(NN, n0 + 512);
  const int nn = n1 - n0;
  const int tid = threadIdx.x;
  for (int i = tid; i < 512; i += 256) { hist[i] = 0; lcur[i] = 0; }
  __syncthreads();
  const int b0 = bbase[c];
  const int b1 = bbase[c + 1];
  for (int i = b0 + tid; i < b1; i += 256)
    atomicAdd(&hist[ebd[i].x - n0], 1);
  __syncthreads();
  int a0 = hist[2 * tid], a1 = hist[2 * tid + 1];
  s2[tid] = a0 + a1;
  __syncthreads();
  for (int off = 1; off < 256; off <<= 1) {
    int u = (tid >= off) ? s2[tid - off] : 0;
    __syncthreads();
    s2[tid] += u;
    __syncthreads();
  }
  int pe = tid ? s2[tid - 1] : 0;
  excl[2 * tid] = pe;
  excl[2 * tid + 1] = pe + a0;
  if (2 * tid < nn)     rp[n0 + 2 * tid]     = b0 + pe;
  if (2 * tid + 1 < nn) rp[n0 + 2 * tid + 1] = b0 + pe + a0;
  __syncthreads();
  for (int i = b0 + tid; i < b1; i += 256) {
    int4 p = ebd[i];
    int li = p.x - n0;
    int k = atomicAdd(&lcur[li], 1);
    int2 q; q.x = p.y; q.y = p.z;
    sw[b0 + excl[li] + k] = q;
  }
}

// ---------------------------------------------------------------------------
// CSR spmm on compact 64-wide f32 rows: one wave per dst node, lane owns one
// column. 8-deep load batching (VGPR 40, ~52% occupancy — the measured
// optimum; 16-deep regressed to 26% occupancy in round 15). Int fixed-point
// accumulate -> bit-deterministic.
//  MODE 1: out = acc*INVS + bias[lane]
//  MODE 2: out = n[d]*P[d,lane] + (1-n[d])*acc*INVS + bias[lane]
// ---------------------------------------------------------------------------
template<int MODE>
__global__ __launch_bounds__(256)
void spmm64(const int* __restrict__ rp, const int2* __restrict__ sw,
            const float* __restrict__ Gf, float* __restrict__ xout,
            const float* __restrict__ bias, const float* __restrict__ npar,
            const float* __restrict__ Pb)
{
  int widx = blockIdx.x * 4 + (threadIdx.x >> 6);
  if (widx >= NN) return;
  int lane = threadIdx.x & 63;
  int e0 = rp[widx], e1 = rp[widx + 1];
  int acc = 0;
  int j = e0;
  for (; j + 8 <= e1; j += 8) {
    float gv[8], wv[8];
#pragma unroll
    for (int u = 0; u < 8; ++u) {
      int2 q = sw[j + u];                       // wave-uniform -> broadcast
      wv[u] = __int_as_float(q.y);
      gv[u] = Gf[(size_t)q.x * 64 + lane];
    }
#pragma unroll
    for (int u = 0; u < 8; ++u)
      acc += __float2int_rn(gv[u] * wv[u] * FIXS);
  }
  for (; j < e1; ++j) {
    int2 q = sw[j];
    acc += __float2int_rn(Gf[(size_t)q.x * 64 + lane] *
                          __int_as_float(q.y) * FIXS);
  }
  float v = (float)acc * INVS;
  if (MODE == 1) {
    xout[(size_t)widx * 64 + lane] = v + bias[lane];
  } else {
    float nv = npar[widx];
    float p = Pb[(size_t)widx * 64 + lane];
    xout[(size_t)widx * 64 + lane] = nv * p + (1.f - nv) * v + bias[lane];
  }
}

// ---------------------------------------------------------------------------
// S[b,:] = sum_l Z[bidx[b,l],:] - 49*b2
// ---------------------------------------------------------------------------
__global__ __launch_bounds__(256)
void sumS_k(const float* __restrict__ Z, const int* __restrict__ bidx,
            const float* __restrict__ b2, float* __restrict__ S)
{
  int wv = threadIdx.x >> 6;
  int lane = threadIdx.x & 63;
  int b = blockIdx.x * 4 + wv;
  if (b >= BBB) return;
  const int* bi = bidx + (size_t)b * LLL;
  float s = 0.f;
  for (int l = 0; l < LLL; ++l)
    s += Z[(size_t)bi[l] * 64 + lane];
  S[(size_t)b * 64 + lane] = s - 49.f * b2[lane];
}

// ---------------------------------------------------------------------------
// sel = sum_{z=0..7} P8[z] + l1b  (fixed order -> deterministic)
// ---------------------------------------------------------------------------
__global__ __launch_bounds__(256)
void reduce8_k(const float* __restrict__ P8, const float* __restrict__ l1b,
               float* __restrict__ sel)
{
  int t = blockIdx.x * 256 + threadIdx.x;
  if (t >= BBB * 32) return;
  int r = t >> 5, c4 = t & 31;
  size_t off = (size_t)r * 128 + (c4 << 2);
  const size_t zs = (size_t)BBB * 128;
  float4 o = *(const float4*)(P8 + off);
#pragma unroll
  for (int z = 1; z < 8; ++z) {
    float4 s = *(const float4*)(P8 + z * zs + off);
    o.x += s.x; o.y += s.y; o.z += s.z; o.w += s.w;
  }
  float4 b = *(const float4*)(l1b + (c4 << 2));
  o.x += b.x; o.y += b.y; o.z += b.z; o.w += b.w;
  *(float4*)(sel + off) = o;
}

// ---------------------------------------------------------------------------
// Classifier + argmax (first-max tie-break, matches jnp.argmax).
// ---------------------------------------------------------------------------
__global__ __launch_bounds__(256)
void cls_k(const float* __restrict__ sel, const float* __restrict__ Wc,
           const float* __restrict__ bc, float* __restrict__ outIdx)
{
  int wv = threadIdx.x >> 6;
  int lane = threadIdx.x & 63;
  int b = blockIdx.x * 4 + wv;
  if (b >= BBB) return;
  float logit = -1e30f;
  if (lane < NCLS) {
    float s = bc[lane];
    const float* sr = sel + (size_t)b * DD;
    for (int d = 0; d < DD; ++d) s = fmaf(sr[d], Wc[d * NCLS + lane], s);
    logit = s;
  }
  float best = -1e30f; int bi = 0;
  for (int c = 0; c < NCLS; ++c) {
    float v = __shfl(logit, c, 64);
    if (v > best) { best = v; bi = c; }
  }
  if (lane == 0) outIdx[b] = (float)bi;
}

// ---------------------------------------------------------------------------
extern "C" void kernel_launch(void* const* d_in, const int* in_sizes, int n_in,
                              void* d_out, int out_size, void* d_ws, size_t ws_size,
                              hipStream_t stream)
{
  const float* A1    = (const float*)d_in[0];
  const int*   esrc  = (const int*)d_in[1];
  const int*   edst  = (const int*)d_in[2];
  const float* ew    = (const float*)d_in[3];
  const int*   bidx  = (const int*)d_in[4];   // [B,1,L] == [B*L]
  const float* wgc1  = (const float*)d_in[5];
  const float* bgc1  = (const float*)d_in[6];
  const float* wgc2  = (const float*)d_in[7];
  const float* bgc2  = (const float*)d_in[8];
  const float* npar  = (const float*)d_in[9];
  const float* lin1  = (const float*)d_in[10];
  const float* lin1b = (const float*)d_in[11];
  const float* w2    = (const float*)d_in[12];
  const float* b2    = (const float*)d_in[13];
  const float* l1w   = (const float*)d_in[14];
  const float* l1b   = (const float*)d_in[15];
  const float* clsw  = (const float*)d_in[16];
  const float* clsb  = (const float*)d_in[17];

  float* out = (float*)d_out;
  float* sel = out + BBB;

  // workspace layout (peak ~92.0 MB; proven floor from round 1 is 104.67 MB)
  uint8_t* ws   = (uint8_t*)d_ws;
  int4*    ebd  = (int4*) (ws);                 // 25.6 MB (CSR build)
  float*   Qb   = (float*)(ws);                 // 25.6 MB (after sort_k)
  float*   Z    = (float*)(ws);                 // 25.6 MB (after spmm1)
  float*   Pb   = (float*)(ws + 25600000);      // 25.6 MB
  float*   G    = (float*)(ws + 51200000);      // 25.6 MB
  float*   P8   = (float*)(ws + 51200000);      // 16.8 MB (after spmm2)
  int2*    sw   = (int2*) (ws + 76800000);      // 12.8 MB packed (src,w)
  int*     rp   = (int*)  (ws + 89600000);      //  0.4 MB (N+1)
  int*     gbkt = (int*)  (ws + 90000016);      //  784 B
  int*     gcur = (int*)  (ws + 90001040);      //  784 B
  int*     bbase= (int*)  (ws + 90002064);      //  788 B
  float*   S    = (float*)(ws + 90400528);      //  1.0 MB [B,64]
  float*   T1   = (float*)(ws + 91449104);      // 128 KB
  float*   T2   = (float*)(ws + 91580176);      // 128 KB
  float*   Wab  = (float*)(ws + 91711248);      // 128 KB [256,128]
  float*   ta   = (float*)(ws + 91842320);      // 512 B
  float*   tb   = (float*)(ws + 91842832);      // 512 B
  float*   bab  = (float*)(ws + 91843344);      // 512 B [128]
  float*   bcv  = (float*)(ws + 91843856);      // 256 B [64]
  ushort*  Wfh  = (ushort*)(ws + 91844112);     //  64 KB W frag hi
  ushort*  Wfl  = (ushort*)(ws + 91909648);     //  64 KB W frag lo

  dim3 blk(256);
  const int gEB = (EE + EPB - 1) / EPB;         // 391

  // ---- weight fusion + MFMA fragment pack ----
  hipLaunchKernelGGL(fuse1_k, dim3(257), blk, 0, stream,
      wgc1, lin1, bgc1, lin1b, wgc2, T1, T2, ta, tb);
  hipLaunchKernelGGL(fuse2_k, dim3(129), blk, 0, stream,
      T1, T2, ta, tb, bgc2, w2, Wab, bab, bcv);
  hipLaunchKernelGGL(wfrag_k, dim3(16), blk, 0, stream, Wab, Wfh, Wfl);

  // ---- CSR build (coarse count -> scan -> bin -> per-bucket sort) ----
  hipMemsetAsync(gbkt, 0, NB * 4, stream);
  hipLaunchKernelGGL(cnt_k, dim3(gEB), blk, 0, stream, edst, gbkt);
  hipLaunchKernelGGL(scanB_k, dim3(1), blk, 0, stream, gbkt, bbase, gcur, rp);
  hipLaunchKernelGGL(bin_k, dim3(gEB), blk, 0, stream, edst, esrc, ew, gcur, ebd);
  hipLaunchKernelGGL(sort_k, dim3(NB), blk, 0, stream, ebd, bbase, rp, sw);

  // ---- Q|P = A1 @ Wab + bab via bf16x2-split MFMA (compact [N,64] each) ----
  hipLaunchKernelGGL(gemm_qp_mfma, dim3((NN + 127) / 128), blk, 0, stream,
      A1, Wfh, Wfl, bab, Qb, Pb, NN);

  // ---- G = n*P + (1-n)*spmm(Q) + bc ----
  hipLaunchKernelGGL((spmm64<2>), dim3(NN / 4), blk, 0, stream,
      rp, sw, Qb, G, bcv, npar, Pb);

  // ---- Z = spmm(G) + b2  [N,64] (overwrites Qbuf) ----
  hipLaunchKernelGGL((spmm64<1>), dim3(NN / 4), blk, 0, stream,
      rp, sw, G, Z, b2, (const float*)nullptr, (const float*)nullptr);

  // ---- S[b] = sum_l Z[bidx[b,l]] - 49*b2 ----
  hipLaunchKernelGGL(sumS_k, dim3(BBB / 4), blk, 0, stream, Z, bidx, b2, S);

  // ---- P8[z] = [gather(Z)|S] @ l1w (K-chunk z)  grid (64,2,8) ----
  hipLaunchKernelGGL((gemm_f32<64,64,32,4,4>), dim3(BBB / 64, 2, 8), blk, 0, stream,
      Z, 64, l1w, DD, (const float*)nullptr, P8, DD,
      BBB, (LLL + 1) * 64, 13 * 32, bidx, S);

  // ---- sel = sum_z P8[z] + l1b ----
  hipLaunchKernelGGL(reduce8_k, dim3(BBB * 32 / 256), blk, 0, stream, P8, l1b, sel);

  // ---- argmax(sel @ classifier + bias) -> out[0:B] ----
  hipLaunchKernelGGL(cls_k, dim3(BBB / 4), blk, 0, stream, sel, clsw, clsb, out);
}